// Round 1
// baseline (2198.331 us; speedup 1.0000x reference)
//
#include <hip/hip_runtime.h>
#include <math.h>

// Problem constants
#define BATCH 4096
#define T_ENC 50
#define T_DEC 60
#define HID   128      // H
#define EMB   64       // E
#define DIN   2        // D
#define G4    512      // 4*H
#define MT    16       // batch rows per block
#define NTHR  512      // threads per block (== G4, one gate column per thread)

// Workspace layout (floats):
//   [0      , 65536)  whht  : W_hh^T, (128 k) x (512 n), k-major
//   [65536  , 81920)  w1t   : W1^T,   (128 k) x (128 u)
//   [81920  , 82944)  we    : W_ih @ W_emb, (512 n) x (2 d)
//   [82944  , 83456)  bias0 : b_ih + b_hh
//   [83456  , 83968)  bias1 : bias0 + W_ih @ b_emb
// Total 335872 bytes.

__global__ void prep_whht(const float* __restrict__ whh, float* __restrict__ whht) {
    int idx = blockIdx.x * blockDim.x + threadIdx.x;   // 65536 threads
    int n = idx >> 7;        // row of W_hh (gate index), 0..511
    int k = idx & 127;       // col (hidden index)
    whht[k * G4 + n] = whh[idx];
}

__global__ void prep_w1t(const float* __restrict__ w1, float* __restrict__ w1t) {
    int idx = blockIdx.x * blockDim.x + threadIdx.x;   // 16384 threads
    int u = idx >> 7;
    int k = idx & 127;
    w1t[k * HID + u] = w1[idx];
}

__global__ void prep_misc(const float* __restrict__ wih, const float* __restrict__ wemb,
                          const float* __restrict__ bih, const float* __restrict__ bhh,
                          const float* __restrict__ bemb,
                          float* __restrict__ we, float* __restrict__ bias0,
                          float* __restrict__ bias1) {
    int n = threadIdx.x;     // 512 threads, 1 block
    float s0 = 0.f, s1 = 0.f, sb = 0.f;
    for (int e = 0; e < EMB; ++e) {
        float w = wih[n * EMB + e];
        s0 += w * wemb[e * DIN + 0];
        s1 += w * wemb[e * DIN + 1];
        sb += w * bemb[e];
    }
    we[n * 2 + 0] = s0;
    we[n * 2 + 1] = s1;
    float b = bih[n] + bhh[n];
    bias0[n] = b;            // decoder step 0 (prev is literal zeros, no emb bias)
    bias1[n] = b + sb;       // any step whose input went through the embedding
}

__device__ __forceinline__ float sigm(float x) {
    return 1.f / (1.f + __expf(-x));
}
__device__ __forceinline__ float tanh_fast(float x) {
    // 2*sigmoid(2x)-1 : safe at +-inf (no inf/inf)
    return 2.f / (1.f + __expf(-2.f * x)) - 1.f;
}

__global__ __launch_bounds__(NTHR) void lstm_main(
    const float* __restrict__ history,   // (B, 50, 2)
    const float* __restrict__ whht,      // (128, 512)
    const float* __restrict__ w1t,       // (128, 128)
    const float* __restrict__ we,        // (512, 2)
    const float* __restrict__ bias0,     // (512)
    const float* __restrict__ bias1,     // (512)
    const float* __restrict__ b1,        // (128)
    const float* __restrict__ w2,        // (2, 128)
    const float* __restrict__ b2,        // (2)
    float* __restrict__ out)             // (B, 60, 2)
{
    __shared__ float h_s[MT][HID];                 // 8 KB
    __shared__ float c_s[MT][HID];                 // 8 KB
    __shared__ float gates_s[MT][G4];              // 32 KB (aliased as hid after h-update)
    __shared__ float hist_s[MT * T_ENC * DIN];     // 6.4 KB
    __shared__ float p_s[MT][DIN];
    __shared__ float red_s[32][17];                // padded, ~2.2 KB
    __shared__ float w2_s[2 * HID];                // 1 KB

    float* hid_flat = &gates_s[0][0];              // hid_s[m][u] == hid_flat[m*HID+u]

    const int tid = threadIdx.x;
    const int r0  = blockIdx.x * MT;

    // Stage this block's history tile (coalesced)
    for (int i = tid; i < MT * T_ENC * DIN; i += NTHR)
        hist_s[i] = history[r0 * T_ENC * DIN + i];
    // Zero-init h, c
    for (int i = tid; i < MT * HID; i += NTHR) {
        (&h_s[0][0])[i] = 0.f;
        (&c_s[0][0])[i] = 0.f;
    }
    if (tid < 2 * HID) w2_s[tid] = w2[tid];

    // Per-thread constants: gate column n = tid
    const int   n   = tid;
    const float we0 = we[n * 2 + 0];
    const float we1 = we[n * 2 + 1];
    const float bs0 = bias0[n];
    const float bs1 = bias1[n];
    const int   j   = tid & (HID - 1);  // hidden unit for the update phase
    const int   mg  = tid >> 7;         // 0..3 -> rows mg*4 .. mg*4+3
    const float b1r = b1[j];
    __syncthreads();

    float acc[MT];

    for (int t = 0; t < T_ENC + T_DEC; ++t) {
        const bool enc = (t < T_ENC);

        // ---- gate accumulator init: bias + rank-2 input term ----
        if (enc) {
#pragma unroll
            for (int m = 0; m < MT; ++m) {
                float q0 = hist_s[m * (T_ENC * DIN) + t * DIN + 0];
                float q1 = hist_s[m * (T_ENC * DIN) + t * DIN + 1];
                acc[m] = fmaf(q1, we1, fmaf(q0, we0, bs1));
            }
        } else if (t == T_ENC) {
#pragma unroll
            for (int m = 0; m < MT; ++m) acc[m] = bs0;   // prev == zeros
        } else {
#pragma unroll
            for (int m = 0; m < MT; ++m) {
                float q0 = p_s[m][0];
                float q1 = p_s[m][1];
                acc[m] = fmaf(q1, we1, fmaf(q0, we0, bs1));
            }
        }

        // ---- K=128 recurrent matmul: acc[m] += sum_k h[m][k] * W_hh[n][k] ----
#pragma unroll 2
        for (int k = 0; k < HID; k += 4) {
            float w0 = whht[(k + 0) * G4 + n];
            float w1v = whht[(k + 1) * G4 + n];
            float w2v = whht[(k + 2) * G4 + n];
            float w3v = whht[(k + 3) * G4 + n];
#pragma unroll
            for (int m = 0; m < MT; ++m) {
                const float4 hv = *(const float4*)&h_s[m][k];
                acc[m] = fmaf(hv.w, w3v, fmaf(hv.z, w2v, fmaf(hv.y, w1v, fmaf(hv.x, w0, acc[m]))));
            }
        }
#pragma unroll
        for (int m = 0; m < MT; ++m) gates_s[m][n] = acc[m];
        __syncthreads();

        // ---- LSTM pointwise update: 4 (m, j) pairs per thread ----
#pragma unroll
        for (int q = 0; q < 4; ++q) {
            int m = mg * 4 + q;
            float gi = gates_s[m][j];
            float gf = gates_s[m][HID + j];
            float gg = gates_s[m][2 * HID + j];
            float go = gates_s[m][3 * HID + j];
            float i_ = sigm(gi);
            float f_ = sigm(gf);
            float g_ = tanh_fast(gg);
            float o_ = sigm(go);
            float c  = fmaf(f_, c_s[m][j], i_ * g_);
            c_s[m][j] = c;
            h_s[m][j] = o_ * tanh_fast(c);
        }
        __syncthreads();

        if (!enc) {
            // ---- hid = relu(h @ W1^T + b1): thread -> unit j, rows mg*4..mg*4+3 ----
            float a2[4] = {b1r, b1r, b1r, b1r};
#pragma unroll 2
            for (int k = 0; k < HID; k += 4) {
                float w0 = w1t[(k + 0) * HID + j];
                float w1v = w1t[(k + 1) * HID + j];
                float w2v = w1t[(k + 2) * HID + j];
                float w3v = w1t[(k + 3) * HID + j];
#pragma unroll
                for (int q = 0; q < 4; ++q) {
                    const float4 hv = *(const float4*)&h_s[mg * 4 + q][k];
                    a2[q] = fmaf(hv.w, w3v, fmaf(hv.z, w2v, fmaf(hv.y, w1v, fmaf(hv.x, w0, a2[q]))));
                }
            }
            __syncthreads();   // gates_s reads done; safe to alias as hid
#pragma unroll
            for (int q = 0; q < 4; ++q)
                hid_flat[(mg * 4 + q) * HID + j] = fmaxf(a2[q], 0.f);
            __syncthreads();

            // ---- pred[m][d] = hid[m] . W2[d] + b2[d]: 32 outputs, 16-thread tree each ----
            {
                int oi   = tid >> 4;        // 0..31
                int part = tid & 15;
                int m = oi >> 1, d = oi & 1;
                float s = 0.f;
#pragma unroll
                for (int kk = 0; kk < 8; ++kk)
                    s += hid_flat[m * HID + part * 8 + kk] * w2_s[d * HID + part * 8 + kk];
                red_s[oi][part] = s;
            }
            __syncthreads();
            if (tid < 32) {
                int m = tid >> 1, d = tid & 1;
                float s = b2[d];
#pragma unroll
                for (int kk = 0; kk < 16; ++kk) s += red_s[tid][kk];
                int td = t - T_ENC;
                out[((size_t)(r0 + m) * T_DEC + td) * DIN + d] = s;
                p_s[m][d] = s;
            }
            __syncthreads();
        }
    }
}

extern "C" void kernel_launch(void* const* d_in, const int* in_sizes, int n_in,
                              void* d_out, int out_size, void* d_ws, size_t ws_size,
                              hipStream_t stream) {
    const float* history = (const float*)d_in[0];
    const float* W_emb   = (const float*)d_in[1];
    const float* b_emb   = (const float*)d_in[2];
    const float* W_ih    = (const float*)d_in[3];
    const float* W_hh    = (const float*)d_in[4];
    const float* b_ih    = (const float*)d_in[5];
    const float* b_hh    = (const float*)d_in[6];
    const float* W1      = (const float*)d_in[7];
    const float* b1      = (const float*)d_in[8];
    const float* W2      = (const float*)d_in[9];
    const float* b2      = (const float*)d_in[10];
    float* out = (float*)d_out;
    float* ws  = (float*)d_ws;

    float* whht  = ws;            // 65536
    float* w1t   = ws + 65536;    // 16384
    float* we    = ws + 81920;    // 1024
    float* bias0 = ws + 82944;    // 512
    float* bias1 = ws + 83456;    // 512

    prep_whht<<<65536 / 256, 256, 0, stream>>>(W_hh, whht);
    prep_w1t<<<16384 / 256, 256, 0, stream>>>(W1, w1t);
    prep_misc<<<1, 512, 0, stream>>>(W_ih, W_emb, b_ih, b_hh, b_emb, we, bias0, bias1);

    lstm_main<<<BATCH / MT, NTHR, 0, stream>>>(history, whht, w1t, we, bias0, bias1,
                                               b1, W2, b2, out);
}

// Round 2
// 440.729 us; speedup vs baseline: 4.9879x; 4.9879x over previous
//
#include <hip/hip_runtime.h>
#include <math.h>

// Problem constants
#define T_ENC 50
#define T_DEC 60
#define HID   128
#define EMB   64
#define DIN   2
#define G4    512
#define MT    16      // batch rows per block
#define NTHR  512     // 8 waves

typedef __attribute__((ext_vector_type(8))) short frag8;  // 8 bf16 (4 VGPRs)
typedef __attribute__((ext_vector_type(4))) float f32x4;  // 4 fp32 acc

// Workspace layout (bytes):
//   [0      , 262144)  whh_pk : W_hh^T split-bf16, per-lane fragment order (131072 shorts)
//   [262144 , 327680)  w1_pk  : W1^T  split-bf16, fragment order (32768 shorts)
//   [327680 , 331776)  we     : W_ih @ W_emb, (512 n) x (2 d)  fp32
//   [331776 , 333824)  bias0  : b_ih + b_hh
//   [333824 , 335872)  bias1  : bias0 + W_ih @ b_emb
// Total 335872 bytes.

__device__ __forceinline__ void split2(float x, unsigned short& hi, unsigned short& lo) {
    unsigned u   = __float_as_uint(x);
    unsigned uhi = u & 0xffff0000u;
    float    lof = x - __uint_as_float(uhi);
    hi = (unsigned short)(uhi >> 16);
    lo = (unsigned short)(__float_as_uint(lof) >> 16);
}

__device__ __forceinline__ unsigned pack_split(float x) {
    unsigned u   = __float_as_uint(x);
    unsigned uhi = u & 0xffff0000u;
    float    lof = x - __uint_as_float(uhi);
    return uhi | (__float_as_uint(lof) >> 16);   // [31:16]=hi bf16, [15:0]=lo bf16
}

// One prep kernel: pack W_hh and W1 into per-lane MFMA B-fragment order (split-bf16),
// and compute the folded rank-2 input map + biases.
__global__ void prep_all(const float* __restrict__ whh, const float* __restrict__ w1m,
                         const float* __restrict__ wih, const float* __restrict__ wemb,
                         const float* __restrict__ bih, const float* __restrict__ bhh,
                         const float* __restrict__ bemb,
                         unsigned short* __restrict__ whh_pk, unsigned short* __restrict__ w1_pk,
                         float* __restrict__ we, float* __restrict__ bias0, float* __restrict__ bias1) {
    int idx = blockIdx.x * blockDim.x + threadIdx.x;   // 65536 threads
    {   // W_hh: B[k][n] = W_hh[n][k]; n = ntg*16 + (L&15); k = ks*32 + (L>>4)*8 + j
        int n = idx >> 7, k = idx & 127;
        unsigned short hi, lo;
        split2(whh[idx], hi, lo);
        int ntg = n >> 4;                  // 0..31 (wave*4 + nt)
        int ks  = k >> 5;
        int L   = (n & 15) | (((k >> 3) & 3) << 4);
        int j   = k & 7;
        size_t b0 = ((((size_t)ntg * 4 + ks) * 2 + 0) * 64 + L) * 8 + j;
        size_t b1_ = ((((size_t)ntg * 4 + ks) * 2 + 1) * 64 + L) * 8 + j;
        whh_pk[b0] = hi; whh_pk[b1_] = lo;
    }
    if (idx < 16384) {  // W1: B[k][u] = W1[u][k]; u = w*16 + (L&15)
        int u = idx >> 7, k = idx & 127;
        unsigned short hi, lo;
        split2(w1m[idx], hi, lo);
        int wv = u >> 4;                   // 0..7
        int ks = k >> 5;
        int L  = (u & 15) | (((k >> 3) & 3) << 4);
        int j  = k & 7;
        size_t b0 = (((size_t)wv * 4 + ks) * 2 + 0) * 512 + (size_t)L * 8 + j;
        size_t b1_ = (((size_t)wv * 4 + ks) * 2 + 1) * 512 + (size_t)L * 8 + j;
        w1_pk[b0] = hi; w1_pk[b1_] = lo;
    }
    if (idx < G4) {     // folded input map + biases
        int n = idx;
        float s0 = 0.f, s1 = 0.f, sb = 0.f;
        for (int e = 0; e < EMB; ++e) {
            float w = wih[n * EMB + e];
            s0 += w * wemb[e * DIN + 0];
            s1 += w * wemb[e * DIN + 1];
            sb += w * bemb[e];
        }
        we[n * 2 + 0] = s0;
        we[n * 2 + 1] = s1;
        float b = bih[n] + bhh[n];
        bias0[n] = b;
        bias1[n] = b + sb;
    }
}

__device__ __forceinline__ float sigm(float x) { return 1.f / (1.f + __expf(-x)); }
__device__ __forceinline__ float tanh_fast(float x) { return 2.f / (1.f + __expf(-2.f * x)) - 1.f; }

// Load A-fragment (hi & lo) for k-step `ks` from packed h LDS (rows padded to 132 dwords).
__device__ __forceinline__ void load_afrag(const unsigned* __restrict__ hpk, int L, int ks,
                                           frag8& Ahi, frag8& Alo) {
    const unsigned* hp = hpk + (L & 15) * 132 + ks * 32 + ((L >> 4) * 8);
    uint4 da = *(const uint4*)hp;
    uint4 db = *(const uint4*)(hp + 4);
    union { unsigned u[4]; frag8 f; } hi, lo;
    hi.u[0] = (da.x >> 16) | (da.y & 0xffff0000u);
    hi.u[1] = (da.z >> 16) | (da.w & 0xffff0000u);
    hi.u[2] = (db.x >> 16) | (db.y & 0xffff0000u);
    hi.u[3] = (db.z >> 16) | (db.w & 0xffff0000u);
    lo.u[0] = (da.x & 0xffffu) | (da.y << 16);
    lo.u[1] = (da.z & 0xffffu) | (da.w << 16);
    lo.u[2] = (db.x & 0xffffu) | (db.y << 16);
    lo.u[3] = (db.z & 0xffffu) | (db.w << 16);
    Ahi = hi.f; Alo = lo.f;
}

__global__ __launch_bounds__(NTHR) void lstm_main(
    const float* __restrict__ history,          // (B, 50, 2)
    const unsigned short* __restrict__ whh_pk,  // packed W_hh frags
    const unsigned short* __restrict__ w1_pk,   // packed W1 frags
    const float* __restrict__ we,               // (512, 2)
    const float* __restrict__ bias0,            // (512)
    const float* __restrict__ bias1,            // (512)
    const float* __restrict__ b1,               // (128)
    const float* __restrict__ w2,               // (2, 128)
    const float* __restrict__ b2,               // (2)
    float* __restrict__ out)                    // (B, 60, 2)
{
    __shared__ unsigned h_pk[MT * 132];         // packed hi|lo h, row pad 132 (8.4 KB)
    __shared__ float gates2[G4 * MT];           // n-major, m-minor (32 KB)
    __shared__ float hist_s[MT * T_ENC * DIN];  // 6.4 KB
    __shared__ float hid_s[MT * 132];           // fp32 relu(hid), pad 132 (8.4 KB)
    __shared__ float w2_s[2 * HID];             // 1 KB
    __shared__ float red_s[32][17];             // 2.2 KB
    __shared__ float p_s[MT][DIN];              // prev pred

    const int tid = threadIdx.x;
    const int L   = tid & 63;
    const int w   = tid >> 6;
    const int r0  = blockIdx.x * MT;

    // ---- staging ----
    for (int i = tid; i < MT * T_ENC * DIN; i += NTHR)
        hist_s[i] = history[r0 * T_ENC * DIN + i];
    for (int i = tid; i < MT * 132; i += NTHR)
        h_pk[i] = 0u;
    if (tid < 2 * HID) w2_s[tid] = w2[tid];

    // ---- persistent W_hh fragments: 128 VGPRs ----
    frag8 Bg[4][4][2];
#pragma unroll
    for (int nt = 0; nt < 4; ++nt)
#pragma unroll
        for (int ks = 0; ks < 4; ++ks)
#pragma unroll
            for (int sp = 0; sp < 2; ++sp)
                Bg[nt][ks][sp] = *(const frag8*)(whh_pk +
                    (((((size_t)w * 4 + nt) * 4 + ks) * 2 + sp) * 64 + L) * 8);

    // ---- per-lane constants ----
    const int m0c = (L >> 4) * 4;          // C-fragment row base
    const int nb  = w * 64 + (L & 15);     // gate column base
    float bs1v[4], bs0v[4], we0v[4], we1v[4];
#pragma unroll
    for (int nt = 0; nt < 4; ++nt) {
        int n = nb + nt * 16;
        bs1v[nt] = bias1[n];
        bs0v[nt] = bias0[n];
        we0v[nt] = we[n * 2 + 0];
        we1v[nt] = we[n * 2 + 1];
    }
    const float b1v = b1[w * 16 + (L & 15)];
    const int jj  = (tid >> 2) & 127;      // pointwise: hidden unit
    const int mgq = tid & 3;               // pointwise: row group (4 rows)
    float cst[4] = {0.f, 0.f, 0.f, 0.f};   // c state, rows mgq*4+q, unit jj
    __syncthreads();

    for (int t = 0; t < T_ENC + T_DEC; ++t) {
        const bool dec = (t >= T_ENC);

        // ---- phase A: gates = h @ W_hh^T + (bias + rank-2 input term) ----
        f32x4 acc[4];
        if (t == T_ENC) {
#pragma unroll
            for (int nt = 0; nt < 4; ++nt)
                acc[nt] = (f32x4){bs0v[nt], bs0v[nt], bs0v[nt], bs0v[nt]};
        } else {
            float q0[4], q1[4];
#pragma unroll
            for (int r = 0; r < 4; ++r) {
                int m = m0c + r;
                if (!dec) {
                    float2 q = *(const float2*)&hist_s[m * (T_ENC * DIN) + t * DIN];
                    q0[r] = q.x; q1[r] = q.y;
                } else {
                    q0[r] = p_s[m][0]; q1[r] = p_s[m][1];
                }
            }
#pragma unroll
            for (int nt = 0; nt < 4; ++nt)
#pragma unroll
                for (int r = 0; r < 4; ++r)
                    acc[nt][r] = fmaf(q1[r], we1v[nt], fmaf(q0[r], we0v[nt], bs1v[nt]));
        }

        // prefetch W1 fragments for this decoder step (L2-resident, hidden behind MFMA)
        frag8 Bw1[4][2];
        if (dec) {
#pragma unroll
            for (int ks = 0; ks < 4; ++ks)
#pragma unroll
                for (int sp = 0; sp < 2; ++sp)
                    Bw1[ks][sp] = *(const frag8*)(w1_pk +
                        ((((size_t)w * 4 + ks) * 2 + sp) * 512 + (size_t)L * 8));
        }

#pragma unroll
        for (int ks = 0; ks < 4; ++ks) {
            frag8 Ahi, Alo;
            load_afrag(h_pk, L, ks, Ahi, Alo);
#pragma unroll
            for (int nt = 0; nt < 4; ++nt) {
                acc[nt] = __builtin_amdgcn_mfma_f32_16x16x32_bf16(Ahi, Bg[nt][ks][1], acc[nt], 0, 0, 0);
                acc[nt] = __builtin_amdgcn_mfma_f32_16x16x32_bf16(Alo, Bg[nt][ks][0], acc[nt], 0, 0, 0);
                acc[nt] = __builtin_amdgcn_mfma_f32_16x16x32_bf16(Ahi, Bg[nt][ks][0], acc[nt], 0, 0, 0);
            }
        }
#pragma unroll
        for (int nt = 0; nt < 4; ++nt)
            *(f32x4*)&gates2[(nb + nt * 16) * MT + m0c] = acc[nt];
        __syncthreads();

        // ---- phase B: LSTM pointwise; thread owns (unit jj, rows mgq*4..+3) ----
        {
            f32x4 g0 = *(const f32x4*)&gates2[(0 * HID + jj) * MT + mgq * 4];
            f32x4 g1 = *(const f32x4*)&gates2[(1 * HID + jj) * MT + mgq * 4];
            f32x4 g2 = *(const f32x4*)&gates2[(2 * HID + jj) * MT + mgq * 4];
            f32x4 g3 = *(const f32x4*)&gates2[(3 * HID + jj) * MT + mgq * 4];
#pragma unroll
            for (int q = 0; q < 4; ++q) {
                float i_ = sigm(g0[q]);
                float f_ = sigm(g1[q]);
                float gv = tanh_fast(g2[q]);
                float o_ = sigm(g3[q]);
                cst[q] = fmaf(f_, cst[q], i_ * gv);
                float h = o_ * tanh_fast(cst[q]);
                h_pk[(mgq * 4 + q) * 132 + jj] = pack_split(h);
            }
        }
        __syncthreads();

        // ---- phase C: decoder head ----
        if (dec) {
            // hid = relu(h @ W1^T + b1); wave w owns u-tile w*16..w*16+15
            f32x4 hacc = (f32x4){b1v, b1v, b1v, b1v};
#pragma unroll
            for (int ks = 0; ks < 4; ++ks) {
                frag8 Ahi, Alo;
                load_afrag(h_pk, L, ks, Ahi, Alo);
                hacc = __builtin_amdgcn_mfma_f32_16x16x32_bf16(Ahi, Bw1[ks][1], hacc, 0, 0, 0);
                hacc = __builtin_amdgcn_mfma_f32_16x16x32_bf16(Alo, Bw1[ks][0], hacc, 0, 0, 0);
                hacc = __builtin_amdgcn_mfma_f32_16x16x32_bf16(Ahi, Bw1[ks][0], hacc, 0, 0, 0);
            }
            const int uu = w * 16 + (L & 15);
#pragma unroll
            for (int r = 0; r < 4; ++r)
                hid_s[(m0c + r) * 132 + uu] = fmaxf(hacc[r], 0.f);
            __syncthreads();

            // pred[m][d] = hid[m] . W2[d] + b2[d]: 32 outputs, 16-way partials
            {
                int oi = tid >> 4, part = tid & 15;
                int m = oi >> 1, d = oi & 1;
                const f32x4 ha = *(const f32x4*)&hid_s[m * 132 + part * 8];
                const f32x4 hb = *(const f32x4*)&hid_s[m * 132 + part * 8 + 4];
                const f32x4 wa = *(const f32x4*)&w2_s[d * HID + part * 8];
                const f32x4 wb = *(const f32x4*)&w2_s[d * HID + part * 8 + 4];
                float s = ha.x * wa.x + ha.y * wa.y + ha.z * wa.z + ha.w * wa.w
                        + hb.x * wb.x + hb.y * wb.y + hb.z * wb.z + hb.w * wb.w;
                red_s[oi][part] = s;
            }
            __syncthreads();
            if (tid < 32) {
                int m = tid >> 1, d = tid & 1;
                float s = b2[d];
#pragma unroll
                for (int kk = 0; kk < 16; ++kk) s += red_s[tid][kk];
                out[((size_t)(r0 + m) * T_DEC + (t - T_ENC)) * DIN + d] = s;
                p_s[m][d] = s;
            }
            __syncthreads();
        }
    }
}

extern "C" void kernel_launch(void* const* d_in, const int* in_sizes, int n_in,
                              void* d_out, int out_size, void* d_ws, size_t ws_size,
                              hipStream_t stream) {
    const float* history = (const float*)d_in[0];
    const float* W_emb   = (const float*)d_in[1];
    const float* b_emb   = (const float*)d_in[2];
    const float* W_ih    = (const float*)d_in[3];
    const float* W_hh    = (const float*)d_in[4];
    const float* b_ih    = (const float*)d_in[5];
    const float* b_hh    = (const float*)d_in[6];
    const float* W1      = (const float*)d_in[7];
    const float* b1      = (const float*)d_in[8];
    const float* W2      = (const float*)d_in[9];
    const float* b2      = (const float*)d_in[10];
    float* out = (float*)d_out;

    unsigned short* whh_pk = (unsigned short*)d_ws;
    unsigned short* w1_pk  = (unsigned short*)((char*)d_ws + 262144);
    float* wef   = (float*)((char*)d_ws + 327680);
    float* bias0 = (float*)((char*)d_ws + 331776);
    float* bias1 = (float*)((char*)d_ws + 333824);

    prep_all<<<256, 256, 0, stream>>>(W_hh, W1, W_ih, W_emb, b_ih, b_hh, b_emb,
                                      whh_pk, w1_pk, wef, bias0, bias1);

    lstm_main<<<4096 / MT, NTHR, 0, stream>>>(history, whh_pk, w1_pk, wef, bias0, bias1,
                                              b1, W2, b2, out);
}

// Round 4
// 376.963 us; speedup vs baseline: 5.8317x; 1.1692x over previous
//
#include <hip/hip_runtime.h>
#include <math.h>

// Problem constants
#define T_ENC 50
#define T_DEC 60
#define HID   128
#define EMB   64
#define DIN   2
#define MT    16      // batch rows per block
#define NTHR  512     // 8 waves
#define HS    136     // shorts per h row (pad breaks power-of-2 bank stride)

typedef __attribute__((ext_vector_type(8))) short frag8;  // 8 bf16 (4 VGPRs)
typedef __attribute__((ext_vector_type(4))) float f32x4;  // 4 fp32 acc

__device__ __forceinline__ float sigm(float x) { return 1.f / (1.f + __expf(-x)); }
__device__ __forceinline__ float tanh_fast(float x) { return 2.f / (1.f + __expf(-2.f * x)) - 1.f; }

// Split 8 consecutive floats W[n][kb..kb+7] into hi/lo bf16 A/B-fragment registers.
__device__ __forceinline__ void load_wfrag(const float* __restrict__ wrow,
                                           frag8& Fhi, frag8& Flo) {
    union { unsigned short s[8]; frag8 f; } hi, lo;
#pragma unroll
    for (int j = 0; j < 8; ++j) {
        float x      = wrow[j];
        unsigned u   = __float_as_uint(x);
        unsigned uhi = u & 0xffff0000u;
        float    lof = x - __uint_as_float(uhi);   // exact remainder
        hi.s[j] = (unsigned short)(uhi >> 16);
        lo.s[j] = (unsigned short)(__float_as_uint(lof) >> 16);
    }
    Fhi = hi.f; Flo = lo.f;
}

__device__ __forceinline__ void split2(float x, unsigned short& hi, unsigned short& lo) {
    unsigned u   = __float_as_uint(x);
    unsigned uhi = u & 0xffff0000u;
    float    lof = x - __uint_as_float(uhi);
    hi = (unsigned short)(uhi >> 16);
    lo = (unsigned short)(__float_as_uint(lof) >> 16);
}

// Single fused kernel: no workspace, no inter-kernel handoff.
__global__ __launch_bounds__(NTHR) void lstm_all(
    const float* __restrict__ history,  // (B, 50, 2)
    const float* __restrict__ W_emb,    // (64, 2)
    const float* __restrict__ b_emb,    // (64)
    const float* __restrict__ W_ih,     // (512, 64)
    const float* __restrict__ W_hh,     // (512, 128)
    const float* __restrict__ b_ih,     // (512)
    const float* __restrict__ b_hh,     // (512)
    const float* __restrict__ W1,       // (128, 128)
    const float* __restrict__ b1,       // (128)
    const float* __restrict__ w2,       // (2, 128)
    const float* __restrict__ b2,       // (2)
    float* __restrict__ out)            // (B, 60, 2)
{
    // h state, split-bf16, native A-fragment row layout, SINGLE buffer (2-barrier discipline)
    __shared__ __align__(16) unsigned short hhi[MT * HS];      // 4.3 KB
    __shared__ __align__(16) unsigned short hlo[MT * HS];      // 4.3 KB
    __shared__ float hist_s[MT * T_ENC * DIN];                 // 6.4 KB
    __shared__ float hid_s[MT * 132];                          // 8.4 KB
    __shared__ float w2_s[2 * HID];                            // 1 KB
    __shared__ float red_s[32][17];                            // 2.2 KB
    __shared__ float p_s[MT][DIN];
    __shared__ float wemb_s[EMB * DIN];                        // 0.5 KB
    __shared__ float bemb_s[EMB];                              // 0.25 KB

    const int tid = threadIdx.x;
    const int L   = tid & 63;
    const int w   = tid >> 6;
    const int r0  = blockIdx.x * MT;

    // ---- staging: every LDS word that is ever read gets initialized here ----
    for (int i = tid; i < MT * T_ENC * DIN; i += NTHR)
        hist_s[i] = history[r0 * T_ENC * DIN + i];
    for (int i = tid; i < MT * HS; i += NTHR) { hhi[i] = 0; hlo[i] = 0; }
    for (int i = tid; i < MT * 132; i += NTHR) hid_s[i] = 0.f;
    if (tid < 2 * HID) w2_s[tid] = w2[tid];
    if (tid < EMB * DIN) wemb_s[tid] = W_emb[tid];
    if (tid < EMB) bemb_s[tid] = b_emb[tid];
    if (tid < 32) red_s[tid >> 4][tid & 15] = 0.f;   // fully written later anyway
    if (tid < MT * DIN) p_s[tid >> 1][tid & 1] = 0.f;

    // ---- per-wave weight gather: straight from d_in, split-bf16 in-register ----
    // Fragment mapping (mfma_f32_16x16x32_bf16): A[m=L&15][k=(L>>4)*8+j],
    // B[k][n=L&15], C col=L&15, row=(L>>4)*4+reg.
    const int nc = L & 15;
    const int kb0 = (L >> 4) * 8;
    frag8 Bg[4][4][2];   // [gate][ks][hi/lo] — gate-fused: tile g covers n=g*128+w*16+nc
#pragma unroll
    for (int g = 0; g < 4; ++g)
#pragma unroll
        for (int ks = 0; ks < 4; ++ks) {
            int n = g * HID + w * 16 + nc;
            load_wfrag(&W_hh[(size_t)n * HID + ks * 32 + kb0], Bg[g][ks][0], Bg[g][ks][1]);
        }
    frag8 Bw1[4][2];     // wave w owns u-tile w*16..w*16+15
#pragma unroll
    for (int ks = 0; ks < 4; ++ks) {
        int u = w * 16 + nc;
        load_wfrag(&W1[(size_t)u * HID + ks * 32 + kb0], Bw1[ks][0], Bw1[ks][1]);
    }

    __syncthreads();   // staging (incl. wemb_s/bemb_s) visible

    // ---- per-lane folded constants: we = W_ih @ W_emb (rank-2), biases ----
    const int m0c  = (L >> 4) * 4;                  // C-fragment row base
    const int jcol = w * 16 + nc;                   // owned hidden unit (C col)
    const int fb   = nc * HS + kb0;                 // A-frag base (shorts)
    float bs1v[4], bs0v[4], we0v[4], we1v[4];
#pragma unroll
    for (int g = 0; g < 4; ++g) {
        int n = g * HID + jcol;
        float s0 = 0.f, s1 = 0.f, sb = 0.f;
        const float* wr = &W_ih[(size_t)n * EMB];
#pragma unroll 4
        for (int e4 = 0; e4 < EMB / 4; ++e4) {
            float4 wv = *(const float4*)&wr[e4 * 4];
            int e = e4 * 4;
            s0 += wv.x * wemb_s[(e+0)*2] + wv.y * wemb_s[(e+1)*2]
                + wv.z * wemb_s[(e+2)*2] + wv.w * wemb_s[(e+3)*2];
            s1 += wv.x * wemb_s[(e+0)*2+1] + wv.y * wemb_s[(e+1)*2+1]
                + wv.z * wemb_s[(e+2)*2+1] + wv.w * wemb_s[(e+3)*2+1];
            sb += wv.x * bemb_s[e+0] + wv.y * bemb_s[e+1]
                + wv.z * bemb_s[e+2] + wv.w * bemb_s[e+3];
        }
        float b = b_ih[n] + b_hh[n];
        bs0v[g] = b;          // decoder step 0: prev is literal zeros (no emb bias)
        bs1v[g] = b + sb;     // input went through embedding
        we0v[g] = s0; we1v[g] = s1;
    }
    const float b1v = b1[jcol];
    const float b2v0 = b2[0], b2v1 = b2[1];
    float cst[4] = {0.f, 0.f, 0.f, 0.f};   // c state: rows m0c+r, unit jcol

    // =================== encoder ===================
#pragma unroll 1
    for (int t = 0; t < T_ENC; ++t) {
        f32x4 acc[4];
        float q0[4], q1[4];
#pragma unroll
        for (int r = 0; r < 4; ++r) {
            float2 q = *(const float2*)&hist_s[(m0c + r) * (T_ENC * DIN) + t * DIN];
            q0[r] = q.x; q1[r] = q.y;
        }
#pragma unroll
        for (int g = 0; g < 4; ++g)
#pragma unroll
            for (int r = 0; r < 4; ++r)
                acc[g][r] = fmaf(q1[r], we1v[g], fmaf(q0[r], we0v[g], bs1v[g]));

#pragma unroll
        for (int ks = 0; ks < 4; ++ks) {
            frag8 Ahi = *(const frag8*)(hhi + fb + ks * 32);
            frag8 Alo = *(const frag8*)(hlo + fb + ks * 32);
#pragma unroll
            for (int g = 0; g < 4; ++g) {
                acc[g] = __builtin_amdgcn_mfma_f32_16x16x32_bf16(Ahi, Bg[g][ks][1], acc[g], 0, 0, 0);
                acc[g] = __builtin_amdgcn_mfma_f32_16x16x32_bf16(Alo, Bg[g][ks][0], acc[g], 0, 0, 0);
                acc[g] = __builtin_amdgcn_mfma_f32_16x16x32_bf16(Ahi, Bg[g][ks][0], acc[g], 0, 0, 0);
            }
        }
        __syncthreads();   // all reads of h done before overwrite

#pragma unroll
        for (int r = 0; r < 4; ++r) {
            float i_ = sigm(acc[0][r]);
            float f_ = sigm(acc[1][r]);
            float gv = tanh_fast(acc[2][r]);
            float o_ = sigm(acc[3][r]);
            cst[r] = fmaf(f_, cst[r], i_ * gv);
            float h = o_ * tanh_fast(cst[r]);
            unsigned short phi, plo;
            split2(h, phi, plo);
            hhi[(m0c + r) * HS + jcol] = phi;
            hlo[(m0c + r) * HS + jcol] = plo;
        }
        __syncthreads();   // new h visible
    }

    // =================== decoder ===================
#pragma unroll 1
    for (int td = 0; td < T_DEC; ++td) {
        f32x4 acc[4];
        if (td == 0) {
#pragma unroll
            for (int g = 0; g < 4; ++g)
                acc[g] = (f32x4){bs0v[g], bs0v[g], bs0v[g], bs0v[g]};
        } else {
            float q0[4], q1[4];
#pragma unroll
            for (int r = 0; r < 4; ++r) { q0[r] = p_s[m0c + r][0]; q1[r] = p_s[m0c + r][1]; }
#pragma unroll
            for (int g = 0; g < 4; ++g)
#pragma unroll
                for (int r = 0; r < 4; ++r)
                    acc[g][r] = fmaf(q1[r], we1v[g], fmaf(q0[r], we0v[g], bs1v[g]));
        }

#pragma unroll
        for (int ks = 0; ks < 4; ++ks) {
            frag8 Ahi = *(const frag8*)(hhi + fb + ks * 32);
            frag8 Alo = *(const frag8*)(hlo + fb + ks * 32);
#pragma unroll
            for (int g = 0; g < 4; ++g) {
                acc[g] = __builtin_amdgcn_mfma_f32_16x16x32_bf16(Ahi, Bg[g][ks][1], acc[g], 0, 0, 0);
                acc[g] = __builtin_amdgcn_mfma_f32_16x16x32_bf16(Alo, Bg[g][ks][0], acc[g], 0, 0, 0);
                acc[g] = __builtin_amdgcn_mfma_f32_16x16x32_bf16(Ahi, Bg[g][ks][0], acc[g], 0, 0, 0);
            }
        }
        __syncthreads();   // reads done before overwrite

#pragma unroll
        for (int r = 0; r < 4; ++r) {
            float i_ = sigm(acc[0][r]);
            float f_ = sigm(acc[1][r]);
            float gv = tanh_fast(acc[2][r]);
            float o_ = sigm(acc[3][r]);
            cst[r] = fmaf(f_, cst[r], i_ * gv);
            float h = o_ * tanh_fast(cst[r]);
            unsigned short phi, plo;
            split2(h, phi, plo);
            hhi[(m0c + r) * HS + jcol] = phi;
            hlo[(m0c + r) * HS + jcol] = plo;
        }
        __syncthreads();   // new h visible

        // ---- head: hid = relu(h @ W1^T + b1) ----
        f32x4 hacc = (f32x4){b1v, b1v, b1v, b1v};
#pragma unroll
        for (int ks = 0; ks < 4; ++ks) {
            frag8 Ahi = *(const frag8*)(hhi + fb + ks * 32);
            frag8 Alo = *(const frag8*)(hlo + fb + ks * 32);
            hacc = __builtin_amdgcn_mfma_f32_16x16x32_bf16(Ahi, Bw1[ks][1], hacc, 0, 0, 0);
            hacc = __builtin_amdgcn_mfma_f32_16x16x32_bf16(Alo, Bw1[ks][0], hacc, 0, 0, 0);
            hacc = __builtin_amdgcn_mfma_f32_16x16x32_bf16(Ahi, Bw1[ks][0], hacc, 0, 0, 0);
        }
#pragma unroll
        for (int r = 0; r < 4; ++r)
            hid_s[(m0c + r) * 132 + jcol] = fmaxf(hacc[r], 0.f);
        __syncthreads();

        {   // pred[m][d] = hid[m] . W2[d] + b2[d]: 32 outputs, 16-way partials
            int oi = tid >> 4, part = tid & 15;
            int m = oi >> 1, d = oi & 1;
            const f32x4 ha = *(const f32x4*)&hid_s[m * 132 + part * 8];
            const f32x4 hb = *(const f32x4*)&hid_s[m * 132 + part * 8 + 4];
            const f32x4 wa = *(const f32x4*)&w2_s[d * HID + part * 8];
            const f32x4 wb = *(const f32x4*)&w2_s[d * HID + part * 8 + 4];
            red_s[oi][part] = ha.x*wa.x + ha.y*wa.y + ha.z*wa.z + ha.w*wa.w
                            + hb.x*wb.x + hb.y*wb.y + hb.z*wb.z + hb.w*wb.w;
        }
        __syncthreads();
        if (tid < 32) {
            int m = tid >> 1, d = tid & 1;
            float s = (d == 0) ? b2v0 : b2v1;
#pragma unroll
            for (int kk = 0; kk < 16; ++kk) s += red_s[tid][kk];
            out[((size_t)(r0 + m) * T_DEC + td) * DIN + d] = s;
            p_s[m][d] = s;
        }
        __syncthreads();
    }
}

extern "C" void kernel_launch(void* const* d_in, const int* in_sizes, int n_in,
                              void* d_out, int out_size, void* d_ws, size_t ws_size,
                              hipStream_t stream) {
    const float* history = (const float*)d_in[0];
    const float* W_emb   = (const float*)d_in[1];
    const float* b_emb   = (const float*)d_in[2];
    const float* W_ih    = (const float*)d_in[3];
    const float* W_hh    = (const float*)d_in[4];
    const float* b_ih    = (const float*)d_in[5];
    const float* b_hh    = (const float*)d_in[6];
    const float* W1      = (const float*)d_in[7];
    const float* b1      = (const float*)d_in[8];
    const float* W2      = (const float*)d_in[9];
    const float* b2      = (const float*)d_in[10];
    float* out = (float*)d_out;
    (void)d_ws; (void)ws_size; (void)in_sizes; (void)n_in; (void)out_size;

    lstm_all<<<4096 / MT, NTHR, 0, stream>>>(history, W_emb, b_emb, W_ih, W_hh,
                                             b_ih, b_hh, W1, b1, W2, b2, out);
}